// Round 11
// baseline (959.117 us; speedup 1.0000x reference)
//
#include <hip/hip_runtime.h>

#define B_ 128
#define K_ 25
#define DEG_ 16

#define R4(X) X(0) X(1) X(2) X(3)

typedef __attribute__((ext_vector_type(4))) float f32x4;
typedef __attribute__((ext_vector_type(8))) short bf16x8;

__device__ __forceinline__ float4 f4ma(float t, float4 w, float4 a) {
    a.x = fmaf(t, w.x, a.x); a.y = fmaf(t, w.y, a.y);
    a.z = fmaf(t, w.z, a.z); a.w = fmaf(t, w.w, a.w);
    return a;
}
__device__ __forceinline__ float4 f4max(float4 a, float4 b) {
    return make_float4(fmaxf(a.x, b.x), fmaxf(a.y, b.y), fmaxf(a.z, b.z), fmaxf(a.w, b.w));
}
__device__ __forceinline__ float4 f4sub2(float4 s, float4 p) {
    return make_float4(2.f * s.x - p.x, 2.f * s.y - p.y, 2.f * s.z - p.z, 2.f * s.w - p.w);
}
// bf16 pack (RTNE)
__device__ __forceinline__ unsigned f2bfu(float f) {
    unsigned u = __float_as_uint(f);
    return (u + 0x7FFFu + ((u >> 16) & 1u)) >> 16;
}
__device__ __forceinline__ unsigned packbf(float e, float o) { return f2bfu(e) | (f2bfu(o) << 16); }

__device__ __forceinline__ bf16x8 u2b(uint4 u) {
    union { uint4 u4; bf16x8 b8; } c; c.u4 = u; return c.b8;
}
__device__ __forceinline__ f32x4 mfma_bf(uint4 a, uint4 b, f32x4 c) {
    return __builtin_amdgcn_mfma_f32_16x16x32_bf16(u2b(a), u2b(b), c, 0, 0, 0);
}

// ======== layouts ========
// layer-2 state (fp32, slab-major): slab s=(fi>>1)*32+(b>>2); addr = s*8192 + v*8 + (fi&1)*4 + (b&3)
// layer-2 mirror (bf16 pairs): dword addr = ((fi>>1)*32 + (b>>2))*4096 + v*4 + (b&3); slot = 2097152 dwords
// layer-3 state: slab s=(fi>>1)*8+(b>>4); addr = s*8192 + v*32 + (fi&1)*16 + (b&15)
// layer-3 mirror: dword addr = ((fi>>1)*8 + (b>>4))*4096 + v*16 + (b&15); slot = 1048576 dwords

// ---------------- transpose x: (B=128, N=4096) -> x0 (4096, 128)
__global__ __launch_bounds__(256) void k_transpose_x(const float* __restrict__ x, float* __restrict__ x0) {
    int i = blockIdx.x * 256 + threadIdx.x;   // i = v*128 + b
    int v = i >> 7, b = i & 127;
    x0[i] = x[(b << 12) + v];
}

// ---------------- prepack W2/W3 -> bf16 [k][fo][fi]
__global__ __launch_bounds__(256) void k_packw(const float* __restrict__ w2, const float* __restrict__ w3,
        unsigned short* __restrict__ wb2, unsigned short* __restrict__ wb3) {
    int i = blockIdx.x * 256 + threadIdx.x;
    if (i < 51200) {        // 25*64*32
        int k = i >> 11, rem = i & 2047, fo = rem >> 5, fi = rem & 31;
        wb2[i] = (unsigned short)f2bfu(w2[(size_t)(fi * K_ + k) * 64 + fo]);
    }
    if (i < 102400) {       // 25*64*64
        int k = i >> 12, rem = i & 4095, fo = rem >> 6, fi = rem & 63;
        wb3[i] = (unsigned short)f2bfu(w3[(size_t)(fi * K_ + k) * 64 + fo]);
    }
}

// ---------------- layer-1 SpMM: one wave per row v, lane = float2 column (C=128 -> 64 f2)
__global__ __launch_bounds__(256) void k_spmm1(const int* __restrict__ cols, const float* __restrict__ vals,
        const float2* __restrict__ cur, const float2* __restrict__ prev,
        float2* __restrict__ next, int two) {
    int t = blockIdx.x * 256 + threadIdx.x;
    int v = __builtin_amdgcn_readfirstlane(t >> 6);
    int lane = threadIdx.x & 63;
    int base = v * DEG_;
    float2 s = make_float2(0.f, 0.f);
#pragma unroll
    for (int d = 0; d < DEG_; ++d) {
        float wv = vals[base + d];
        float2 xx = cur[((size_t)cols[base + d] << 6) + lane];
        s.x = fmaf(wv, xx.x, s.x); s.y = fmaf(wv, xx.y, s.y);
    }
    size_t idx = ((size_t)v << 6) + lane;
    if (two) {
        float2 p = prev[idx];
        s.x = 2.f * s.x - p.x; s.y = 2.f * s.y - p.y;
    }
    next[idx] = s;
}

// ---------------- layer-2 LDS-resident chain: wg = slab of 8 cols (2 fi x 4 b), runs nsteps
__global__ __launch_bounds__(256) void k_chain2(const int* __restrict__ cols, const float* __restrict__ vals,
        float* __restrict__ stA, float* __restrict__ stB, unsigned* __restrict__ mir,
        int k0, int nsteps) {
    __shared__ float st[2][8192];
    int s = blockIdx.x, t = threadIdx.x;
    size_t sb = (size_t)s * 8192;
#pragma unroll
    for (int r = 0; r < 4; ++r) {
        int v = t + (r << 8);
        *(float4*)&st[0][v*8]     = *(const float4*)(stA + sb + v*8);
        *(float4*)&st[0][v*8 + 4] = *(const float4*)(stA + sb + v*8 + 4);
        *(float4*)&st[1][v*8]     = *(const float4*)(stB + sb + v*8);
        *(float4*)&st[1][v*8 + 4] = *(const float4*)(stB + sb + v*8 + 4);
    }
    __syncthreads();
    int pc = 0, pb = 1;
    for (int step = 0; step < nsteps; ++step) {
        int k = k0 + step;
        float4 n0_0, n1_0, n0_1, n1_1, n0_2, n1_2, n0_3, n1_3;
#define C2_CMP(r, N0, N1) { \
        int v = t + (r << 8); \
        const int4* cp = (const int4*)(cols + v * 16); \
        const float4* vp = (const float4*)(vals + v * 16); \
        float4 a0 = make_float4(0.f,0.f,0.f,0.f), a1 = a0; \
        for (int dd = 0; dd < 4; ++dd) { \
            int4 cc = cp[dd]; float4 ww = vp[dd]; \
            const float* p; \
            p = &st[pc][cc.x * 8]; a0 = f4ma(ww.x, *(const float4*)p, a0); a1 = f4ma(ww.x, *(const float4*)(p+4), a1); \
            p = &st[pc][cc.y * 8]; a0 = f4ma(ww.y, *(const float4*)p, a0); a1 = f4ma(ww.y, *(const float4*)(p+4), a1); \
            p = &st[pc][cc.z * 8]; a0 = f4ma(ww.z, *(const float4*)p, a0); a1 = f4ma(ww.z, *(const float4*)(p+4), a1); \
            p = &st[pc][cc.w * 8]; a0 = f4ma(ww.w, *(const float4*)p, a0); a1 = f4ma(ww.w, *(const float4*)(p+4), a1); \
        } \
        if (k >= 2) { \
            float4 p0 = *(const float4*)&st[pb][v*8], p1 = *(const float4*)&st[pb][v*8+4]; \
            a0 = f4sub2(a0, p0); a1 = f4sub2(a1, p1); \
        } \
        N0 = a0; N1 = a1; }
        C2_CMP(0, n0_0, n1_0)
        C2_CMP(1, n0_1, n1_1)
        C2_CMP(2, n0_2, n1_2)
        C2_CMP(3, n0_3, n1_3)
#undef C2_CMP
        __syncthreads();
        unsigned* ms = mir + (size_t)(k % 5) * 2097152 + (size_t)s * 4096;
#define C2_ST(r, N0, N1) { \
        int v = t + (r << 8); \
        *(float4*)&st[pb][v*8] = N0; *(float4*)&st[pb][v*8+4] = N1; \
        uint4 mw = make_uint4(packbf(N0.x, N1.x), packbf(N0.y, N1.y), packbf(N0.z, N1.z), packbf(N0.w, N1.w)); \
        *(uint4*)(ms + v * 4) = mw; }
        C2_ST(0, n0_0, n1_0)
        C2_ST(1, n0_1, n1_1)
        C2_ST(2, n0_2, n1_2)
        C2_ST(3, n0_3, n1_3)
#undef C2_ST
        __syncthreads();
        int tmp = pc; pc = pb; pb = tmp;
    }
#pragma unroll
    for (int r = 0; r < 4; ++r) {
        int v = t + (r << 8);
        *(float4*)(stA + sb + v*8)     = *(const float4*)&st[pc][v*8];
        *(float4*)(stA + sb + v*8 + 4) = *(const float4*)&st[pc][v*8+4];
        *(float4*)(stB + sb + v*8)     = *(const float4*)&st[pb][v*8];
        *(float4*)(stB + sb + v*8 + 4) = *(const float4*)&st[pb][v*8+4];
    }
}

// ---------------- layer-3 LDS-resident chain: wg = slab of 32 cols (2 fi x 16 b); 512 thr = 256 v x 2 halves
__global__ __launch_bounds__(512) void k_chain3(const int* __restrict__ cols, const float* __restrict__ vals,
        float* __restrict__ stA, float* __restrict__ stB, unsigned* __restrict__ mir,
        int k0, int nsteps) {
    __shared__ float st[2][8192];
    int s = blockIdx.x, t = threadIdx.x;
    int v = t >> 1, h = t & 1;
    int o0 = v * 32 + h * 8;
    size_t sb = (size_t)s * 8192;
    *(float4*)&st[0][o0]      = *(const float4*)(stA + sb + o0);
    *(float4*)&st[0][o0 + 4]  = *(const float4*)(stA + sb + o0 + 4);
    *(float4*)&st[0][o0 + 16] = *(const float4*)(stA + sb + o0 + 16);
    *(float4*)&st[0][o0 + 20] = *(const float4*)(stA + sb + o0 + 20);
    *(float4*)&st[1][o0]      = *(const float4*)(stB + sb + o0);
    *(float4*)&st[1][o0 + 4]  = *(const float4*)(stB + sb + o0 + 4);
    *(float4*)&st[1][o0 + 16] = *(const float4*)(stB + sb + o0 + 16);
    *(float4*)&st[1][o0 + 20] = *(const float4*)(stB + sb + o0 + 20);
    __syncthreads();
    int pc = 0, pb = 1;
    const int4* cp = (const int4*)(cols + v * 16);
    const float4* vp = (const float4*)(vals + v * 16);
    for (int step = 0; step < nsteps; ++step) {
        int k = k0 + step;
        float4 ae0 = make_float4(0.f,0.f,0.f,0.f), ae1 = ae0, ao0 = ae0, ao1 = ae0;
        for (int dd = 0; dd < 4; ++dd) {
            int4 cc = cp[dd]; float4 ww = vp[dd];
            const float* p;
            p = &st[pc][cc.x * 32 + h * 8];
            ae0 = f4ma(ww.x, *(const float4*)p, ae0);       ae1 = f4ma(ww.x, *(const float4*)(p+4), ae1);
            ao0 = f4ma(ww.x, *(const float4*)(p+16), ao0);  ao1 = f4ma(ww.x, *(const float4*)(p+20), ao1);
            p = &st[pc][cc.y * 32 + h * 8];
            ae0 = f4ma(ww.y, *(const float4*)p, ae0);       ae1 = f4ma(ww.y, *(const float4*)(p+4), ae1);
            ao0 = f4ma(ww.y, *(const float4*)(p+16), ao0);  ao1 = f4ma(ww.y, *(const float4*)(p+20), ao1);
            p = &st[pc][cc.z * 32 + h * 8];
            ae0 = f4ma(ww.z, *(const float4*)p, ae0);       ae1 = f4ma(ww.z, *(const float4*)(p+4), ae1);
            ao0 = f4ma(ww.z, *(const float4*)(p+16), ao0);  ao1 = f4ma(ww.z, *(const float4*)(p+20), ao1);
            p = &st[pc][cc.w * 32 + h * 8];
            ae0 = f4ma(ww.w, *(const float4*)p, ae0);       ae1 = f4ma(ww.w, *(const float4*)(p+4), ae1);
            ao0 = f4ma(ww.w, *(const float4*)(p+16), ao0);  ao1 = f4ma(ww.w, *(const float4*)(p+20), ao1);
        }
        if (k >= 2) {
            ae0 = f4sub2(ae0, *(const float4*)&st[pb][o0]);
            ae1 = f4sub2(ae1, *(const float4*)&st[pb][o0 + 4]);
            ao0 = f4sub2(ao0, *(const float4*)&st[pb][o0 + 16]);
            ao1 = f4sub2(ao1, *(const float4*)&st[pb][o0 + 20]);
        }
        __syncthreads();
        *(float4*)&st[pb][o0]      = ae0;
        *(float4*)&st[pb][o0 + 4]  = ae1;
        *(float4*)&st[pb][o0 + 16] = ao0;
        *(float4*)&st[pb][o0 + 20] = ao1;
        unsigned* ms = mir + (size_t)(k % 5) * 1048576 + (size_t)s * 4096 + v * 16 + h * 8;
        uint4 w0 = make_uint4(packbf(ae0.x, ao0.x), packbf(ae0.y, ao0.y), packbf(ae0.z, ao0.z), packbf(ae0.w, ao0.w));
        uint4 w1 = make_uint4(packbf(ae1.x, ao1.x), packbf(ae1.y, ao1.y), packbf(ae1.z, ao1.z), packbf(ae1.w, ao1.w));
        *(uint4*)(ms) = w0;
        *(uint4*)(ms + 4) = w1;
        __syncthreads();
        int tmp = pc; pc = pb; pb = tmp;
    }
    *(float4*)(stA + sb + o0)      = *(const float4*)&st[pc][o0];
    *(float4*)(stA + sb + o0 + 4)  = *(const float4*)&st[pc][o0 + 4];
    *(float4*)(stA + sb + o0 + 16) = *(const float4*)&st[pc][o0 + 16];
    *(float4*)(stA + sb + o0 + 20) = *(const float4*)&st[pc][o0 + 20];
    *(float4*)(stB + sb + o0)      = *(const float4*)&st[pb][o0];
    *(float4*)(stB + sb + o0 + 4)  = *(const float4*)&st[pb][o0 + 4];
    *(float4*)(stB + sb + o0 + 16) = *(const float4*)&st[pb][o0 + 16];
    *(float4*)(stB + sb + o0 + 20) = *(const float4*)&st[pb][o0 + 20];
}

// ---------------- layer 1 projection + bias + relu + pool4 -> layer-2 state (slab-major) + mirror slot0
__global__ __launch_bounds__(256) void k_proj1_pool(const float* __restrict__ basis,
        const float* __restrict__ W1, const float* __restrict__ b1, float* __restrict__ st2,
        unsigned* __restrict__ mir) {
    int half = blockIdx.y;
    int i = blockIdx.x * 256 + threadIdx.x;   // i = g*128 + b; g = layer-2 v (0..1023)
    int g = i >> 7, b = i & 127;
    const float* wbase = W1 + half * 16;
#define P1_DM(j) float4 M##j = make_float4(-1e30f, -1e30f, -1e30f, -1e30f);
    R4(P1_DM)
#undef P1_DM
    for (int r = 0; r < 4; ++r) {
        const float* bp = basis + (((size_t)(4 * g + r) << 7) + b);
#define P1_DC(j) float4 C##j = make_float4(0.f, 0.f, 0.f, 0.f);
        R4(P1_DC)
#undef P1_DC
#pragma unroll 5
        for (int k = 0; k < K_; ++k) {
            float tv = bp[(size_t)k * 524288];
            const float4* w = (const float4*)(wbase + k * 32);
#define P1_FM(j) C##j = f4ma(tv, w[j], C##j);
            R4(P1_FM)
#undef P1_FM
        }
#define P1_MX(j) M##j = f4max(M##j, C##j);
        R4(P1_MX)
#undef P1_MX
    }
    const float* bb = b1 + half * 16;
    int bq = b >> 2, bo = b & 3;
#define P1_ST(j) { \
    float e0 = fmaxf(M##j.x + bb[4*j+0], 0.f); \
    float o0 = fmaxf(M##j.y + bb[4*j+1], 0.f); \
    float e1 = fmaxf(M##j.z + bb[4*j+2], 0.f); \
    float o1 = fmaxf(M##j.w + bb[4*j+3], 0.f); \
    int f2a = half * 8 + 2 * j; \
    float* sa = st2 + ((size_t)(f2a * 32 + bq)) * 8192 + g * 8 + bo; \
    float* sbp = st2 + ((size_t)((f2a + 1) * 32 + bq)) * 8192 + g * 8 + bo; \
    sa[0] = e0; sa[4] = o0; sbp[0] = e1; sbp[4] = o1; \
    mir[((size_t)(f2a * 32 + bq)) * 4096 + g * 4 + bo] = packbf(e0, o0); \
    mir[((size_t)((f2a + 1) * 32 + bq)) * 4096 + g * 4 + bo] = packbf(e1, o1); }
    R4(P1_ST)
#undef P1_ST
}

// ---------------- layer-2 chunk projection via MFMA (reads slab-major mirror)
__global__ __launch_bounds__(256) void k_proj_l2m(const unsigned* __restrict__ mir, size_t slotH,
        const uint4* __restrict__ wb, float* __restrict__ acc, int k0, int init,
        const float* __restrict__ bias) {
    int wid = blockIdx.x * 4 + (threadIdx.x >> 6);   // 8192 waves
    int lane = threadIdx.x & 63;
    int lm = lane & 15, lg = lane >> 4;
    int v = wid >> 3, b0 = (wid & 7) << 4;
    float* ap = acc + ((size_t)v << 13) + b0 + (lg << 2);
    f32x4 C0, C1, C2, C3;
    if (init) {
        float q0 = bias[lm], q1 = bias[16 + lm], q2 = bias[32 + lm], q3 = bias[48 + lm];
        C0 = f32x4{q0, q0, q0, q0}; C1 = f32x4{q1, q1, q1, q1};
        C2 = f32x4{q2, q2, q2, q2}; C3 = f32x4{q3, q3, q3, q3};
    } else {
        C0 = *(const f32x4*)(ap + (size_t)lm * 128);
        C1 = *(const f32x4*)(ap + (size_t)(16 + lm) * 128);
        C2 = *(const f32x4*)(ap + (size_t)(32 + lm) * 128);
        C3 = *(const f32x4*)(ap + (size_t)(48 + lm) * 128);
    }
    int b = b0 + lm;
    const unsigned* mp0 = mir + ((size_t)((lg << 2) * 32 + (b >> 2))) * 4096 + (size_t)v * 4 + (b & 3);
#pragma unroll
    for (int kk = 0; kk < 5; ++kk) {
        const unsigned* mp = mp0 + (size_t)kk * slotH;
        uint4 a = make_uint4(mp[0], mp[131072], mp[262144], mp[393216]);
        int kb = (k0 + kk) << 6;
        uint4 w0 = wb[(kb + lm) * 4 + lg];
        uint4 w1 = wb[(kb + 16 + lm) * 4 + lg];
        uint4 w2 = wb[(kb + 32 + lm) * 4 + lg];
        uint4 w3 = wb[(kb + 48 + lm) * 4 + lg];
        C0 = mfma_bf(a, w0, C0);
        C1 = mfma_bf(a, w1, C1);
        C2 = mfma_bf(a, w2, C2);
        C3 = mfma_bf(a, w3, C3);
    }
    *(f32x4*)(ap + (size_t)lm * 128) = C0;
    *(f32x4*)(ap + (size_t)(16 + lm) * 128) = C1;
    *(f32x4*)(ap + (size_t)(32 + lm) * 128) = C2;
    *(f32x4*)(ap + (size_t)(48 + lm) * 128) = C3;
}

// ---------------- layer-3 chunk projection via MFMA (reads slab-major mirror)
__global__ __launch_bounds__(256) void k_proj_l3m(const unsigned* __restrict__ mir, size_t slotH,
        const uint4* __restrict__ wb, float* __restrict__ acc, int k0, int init,
        const float* __restrict__ bias, int finalrelu) {
    int wid = blockIdx.x * 4 + (threadIdx.x >> 6);   // 2048 waves
    int lane = threadIdx.x & 63;
    int lm = lane & 15, lg = lane >> 4;
    int v = wid >> 3, b0 = (wid & 7) << 4;
    float* ap = acc + ((size_t)v << 13) + b0 + (lg << 2);
    f32x4 C0, C1, C2, C3;
    if (init) {
        float q0 = bias[lm], q1 = bias[16 + lm], q2 = bias[32 + lm], q3 = bias[48 + lm];
        C0 = f32x4{q0, q0, q0, q0}; C1 = f32x4{q1, q1, q1, q1};
        C2 = f32x4{q2, q2, q2, q2}; C3 = f32x4{q3, q3, q3, q3};
    } else {
        C0 = *(const f32x4*)(ap + (size_t)lm * 128);
        C1 = *(const f32x4*)(ap + (size_t)(16 + lm) * 128);
        C2 = *(const f32x4*)(ap + (size_t)(32 + lm) * 128);
        C3 = *(const f32x4*)(ap + (size_t)(48 + lm) * 128);
    }
    int bq4 = wid & 7;   // b0 >> 4
    const unsigned* mp0 = mir + (size_t)v * 16 + lm;
#pragma unroll
    for (int kk = 0; kk < 5; ++kk) {
        const unsigned* mpk = mp0 + (size_t)kk * slotH;
        int kb = (k0 + kk) << 6;
#pragma unroll
        for (int ks = 0; ks < 2; ++ks) {
            const unsigned* mk = mpk + ((size_t)(((ks << 4) + (lg << 2)) * 8 + bq4)) * 4096;
            uint4 a = make_uint4(mk[0], mk[32768], mk[65536], mk[98304]);
            int wof = (ks << 2) + lg;
            uint4 w0 = wb[(kb + lm) * 8 + wof];
            uint4 w1 = wb[(kb + 16 + lm) * 8 + wof];
            uint4 w2 = wb[(kb + 32 + lm) * 8 + wof];
            uint4 w3 = wb[(kb + 48 + lm) * 8 + wof];
            C0 = mfma_bf(a, w0, C0);
            C1 = mfma_bf(a, w1, C1);
            C2 = mfma_bf(a, w2, C2);
            C3 = mfma_bf(a, w3, C3);
        }
    }
    if (finalrelu) {
#pragma unroll
        for (int r = 0; r < 4; ++r) {
            C0[r] = fmaxf(C0[r], 0.f); C1[r] = fmaxf(C1[r], 0.f);
            C2[r] = fmaxf(C2[r], 0.f); C3[r] = fmaxf(C3[r], 0.f);
        }
    }
    *(f32x4*)(ap + (size_t)lm * 128) = C0;
    *(f32x4*)(ap + (size_t)(16 + lm) * 128) = C1;
    *(f32x4*)(ap + (size_t)(32 + lm) * 128) = C2;
    *(f32x4*)(ap + (size_t)(48 + lm) * 128) = C3;
}

// ---------------- relu + pool4: layer-2 acc -> layer-3 state (slab-major) + mirror slot0
__global__ __launch_bounds__(256) void k_relu_pool_m(const float* __restrict__ acc,
        float* __restrict__ st3, unsigned* __restrict__ mir) {
    int i = blockIdx.x * 256 + threadIdx.x;   // g*4096 + fi2*128 + b; g = layer-3 v (0..255)
    int g = i >> 12, fi2 = (i >> 7) & 31, b = i & 127;
    const float* ap = acc + (((size_t)g << 2) << 13) + (fi2 << 8) + b;
    float me = 0.f, mo = 0.f;
#pragma unroll
    for (int r = 0; r < 4; ++r) {
        me = fmaxf(me, ap[0]); mo = fmaxf(mo, ap[128]);
        ap += 8192;
    }
    int s = fi2 * 8 + (b >> 4), bo = b & 15;
    st3[(size_t)s * 8192 + g * 32 + bo] = me;
    st3[(size_t)s * 8192 + g * 32 + 16 + bo] = mo;
    mir[(size_t)s * 4096 + g * 16 + bo] = packbf(me, mo);
}

// ---------------- FC1 partials: rowsplit 64, 8 b's per thread (round-9 version)
__global__ __launch_bounds__(256) void k_fc1_part(const float* __restrict__ t3, const float* __restrict__ w,
                           float* __restrict__ part) {
    int blk = blockIdx.x;
    int bg = blk >> 7;
    int rs = (blk >> 1) & 63;
    int j = ((blk & 1) << 8) + threadIdx.x;
    int b0 = bg << 3;
    float a0=0.f,a1=0.f,a2=0.f,a3=0.f,a4=0.f,a5=0.f,a6=0.f,a7=0.f;
    int r0 = rs << 8;
#pragma unroll 4
    for (int row = r0; row < r0 + 256; ++row) {
        float wv = w[((size_t)row << 9) + j];
        const float4* tp = (const float4*)(t3 + ((size_t)row << 7) + b0);
        float4 t0 = tp[0], t1 = tp[1];
        a0 = fmaf(t0.x, wv, a0);
        a1 = fmaf(t0.y, wv, a1);
        a2 = fmaf(t0.z, wv, a2);
        a3 = fmaf(t0.w, wv, a3);
        a4 = fmaf(t1.x, wv, a4);
        a5 = fmaf(t1.y, wv, a5);
        a6 = fmaf(t1.z, wv, a6);
        a7 = fmaf(t1.w, wv, a7);
    }
    float* pp = part + (((size_t)(rs << 7) + b0) << 9) + j;
    pp[0*512]=a0; pp[1*512]=a1; pp[2*512]=a2; pp[3*512]=a3;
    pp[4*512]=a4; pp[5*512]=a5; pp[6*512]=a6; pp[7*512]=a7;
}

__global__ __launch_bounds__(256) void k_fc1_red(const float* __restrict__ part, const float* __restrict__ bias,
                          float* __restrict__ h) {
    int i = blockIdx.x * 256 + threadIdx.x;   // i = b*512 + j
    float a = bias[i & 511];
#pragma unroll 8
    for (int rs = 0; rs < 64; ++rs) a += part[((size_t)rs << 16) + i];
    h[i] = a;
}

// ---------------- batchnorm stats over batch (biased var), store mean | inv_std
__global__ void k_bnstats(const float* __restrict__ h, float* __restrict__ mv) {
    __shared__ float s1[128], s2[128];
    int j = blockIdx.x, t = threadIdx.x;
    float v = h[(size_t)t * 512 + j];
    s1[t] = v; s2[t] = v * v;
    __syncthreads();
    for (int o = 64; o > 0; o >>= 1) {
        if (t < o) { s1[t] += s1[t + o]; s2[t] += s2[t + o]; }
        __syncthreads();
    }
    if (t == 0) {
        float m = s1[0] * (1.f / 128.f);
        float var = s2[0] * (1.f / 128.f) - m * m;
        mv[j] = m;
        mv[512 + j] = rsqrtf(var + 1e-5f);
    }
}

// ---------------- BN apply + relu + FC2 + log_softmax, one block per batch row
__global__ void k_head(const float* __restrict__ h, const float* __restrict__ mv,
                       const float* __restrict__ gamma, const float* __restrict__ beta,
                       const float* __restrict__ w2, const float* __restrict__ b2,
                       float* __restrict__ out) {
    __shared__ float hr[512];
    __shared__ float lg[16];
    int b = blockIdx.x, t = threadIdx.x;   // 64 threads
    for (int j = t; j < 512; j += 64) {
        float x = (h[(size_t)b * 512 + j] - mv[j]) * mv[512 + j] * gamma[j] + beta[j];
        hr[j] = fmaxf(x, 0.f);
    }
    __syncthreads();
    if (t < 10) {
        float a = b2[t];
        for (int j = 0; j < 512; ++j) a += hr[j] * w2[j * 10 + t];
        lg[t] = a;
    }
    __syncthreads();
    if (t == 0) {
        float mx = -1e30f;
        for (int q = 0; q < 10; ++q) mx = fmaxf(mx, lg[q]);
        float sum = 0.f;
        for (int q = 0; q < 10; ++q) sum += expf(lg[q] - mx);
        float ls = logf(sum) + mx;
        for (int q = 0; q < 10; ++q) out[b * 10 + q] = lg[q] - ls;
    }
}

extern "C" void kernel_launch(void* const* d_in, const int* in_sizes, int n_in,
                              void* d_out, int out_size, void* d_ws, size_t ws_size,
                              hipStream_t stream) {
    (void)in_sizes; (void)n_in; (void)out_size; (void)ws_size;
    const float* x      = (const float*)d_in[0];
    const int*   l0cols = (const int*)d_in[2];
    const float* l0vals = (const float*)d_in[3];
    const int*   l2cols = (const int*)d_in[5];
    const float* l2vals = (const float*)d_in[6];
    const int*   l4cols = (const int*)d_in[8];
    const float* l4vals = (const float*)d_in[9];
    const float* w1   = (const float*)d_in[10];
    const float* b1   = (const float*)d_in[11];
    const float* w2   = (const float*)d_in[12];
    const float* b2   = (const float*)d_in[13];
    const float* w3   = (const float*)d_in[14];
    const float* b3   = (const float*)d_in[15];
    const float* fc1w = (const float*)d_in[16];
    const float* fc1b = (const float*)d_in[17];
    const float* gam  = (const float*)d_in[18];
    const float* bet  = (const float*)d_in[19];
    const float* fc2w = (const float*)d_in[20];
    const float* fc2b = (const float*)d_in[21];
    float* out = (float*)d_out;

    const size_t S1 = 4096 * 128;    // layer-1 basis slot (floats)
    const size_t S2 = 1024 * 4096;   // layer-2 state size (floats); mirror slot = S2/2 dwords
    const size_t S3 = 256 * 8192;    // layer-3 state size (floats); mirror slot = S3/2 dwords

    float* ws = (float*)d_ws;
    float* basis1 = ws;                                  // 25 slots of S1 (layer-1, fp32)
    float* st2A   = ws + 25 * S1;                        // layer-2 state A (slab-major)
    float* st2B   = st2A + S2;                           // layer-2 state B
    unsigned* mir2 = (unsigned*)(st2B + S2);             // 5 slots of S2/2 dwords (also mir3 ring)
    float* acc3   = (float*)(mir2 + 5 * (S2 / 2));       // S3
    float* h      = acc3 + S3;                           // 65536
    float* mv     = h + 65536;                           // 1024
    unsigned short* wb2 = (unsigned short*)(mv + 1024);  // 51200 bf16
    unsigned short* wb3 = wb2 + 51200;                   // 102400 bf16
    float* acc2   = basis1;                              // alias: 8.39M <= 13.1M, basis1 dead
    float* st3A   = st2A;                                // alias: layer-2 state dead
    float* st3B   = st2B;
    unsigned* mir3 = mir2;
    float* part   = basis1;                              // alias: acc2 dead by then

    k_packw<<<400, 256, 0, stream>>>(w2, w3, wb2, wb3);

    // ---------------- Layer 1: V=4096, C=128, full fp32 basis ----------------
    k_transpose_x<<<2048, 256, 0, stream>>>(x, basis1);
    for (int k = 1; k < 25; ++k) {
        const float* cur  = basis1 + (size_t)(k - 1) * S1;
        const float* prev = (k >= 2) ? basis1 + (size_t)(k - 2) * S1 : cur;
        float* next = basis1 + (size_t)k * S1;
        k_spmm1<<<1024, 256, 0, stream>>>(l0cols, l0vals, (const float2*)cur,
                                          (const float2*)prev, (float2*)next, k >= 2 ? 1 : 0);
    }
    // pool1 -> st2A (slab-major T0) + mir2 slot0
    k_proj1_pool<<<dim3(512, 2), 256, 0, stream>>>(basis1, w1, b1, st2A, mir2);

    // ---------------- Layer 2: V=1024, C=4096, LDS-resident chunks of 5 ----------------
    for (int c = 0; c < 5; ++c) {
        int kk0 = (c == 0) ? 1 : 5 * c;
        int ns  = (c == 0) ? 4 : 5;
        k_chain2<<<512, 256, 0, stream>>>(l2cols, l2vals, st2A, st2B, mir2, kk0, ns);
        k_proj_l2m<<<2048, 256, 0, stream>>>(mir2, S2 / 2, (const uint4*)wb2, acc2, 5 * c,
                                             c == 0 ? 1 : 0, b2);
    }
    k_relu_pool_m<<<4096, 256, 0, stream>>>(acc2, st3A, mir3);

    // ---------------- Layer 3: V=256, C=8192, LDS-resident chunks of 5 ----------------
    for (int c = 0; c < 5; ++c) {
        int kk0 = (c == 0) ? 1 : 5 * c;
        int ns  = (c == 0) ? 4 : 5;
        k_chain3<<<256, 512, 0, stream>>>(l4cols, l4vals, st3A, st3B, mir3, kk0, ns);
        k_proj_l3m<<<512, 256, 0, stream>>>(mir3, S3 / 2, (const uint4*)wb3, acc3, 5 * c,
                                            c == 0 ? 1 : 0, b3, c == 4 ? 1 : 0);
    }

    // ---------------- FC1 + BN + FC2 + log_softmax ----------------
    k_fc1_part<<<2048, 256, 0, stream>>>(acc3, fc1w, part);
    k_fc1_red<<<256, 256, 0, stream>>>(part, fc1b, h);
    k_bnstats<<<512, 128, 0, stream>>>(h, mv);
    k_head<<<128, 64, 0, stream>>>(h, mv, gam, bet, fc2w, fc2b, out);
}